// Round 3
// baseline (42.275 us; speedup 1.0000x reference)
//
#include <hip/hip_runtime.h>

// Problem constants (HierarchicalIntentClassifier: B=8192, D=768, E=8, K=32)
#define BB 8192
#define DD 768
#define EE 8
#define KK 32

typedef short    short8 __attribute__((ext_vector_type(8)));
typedef float    f32x4  __attribute__((ext_vector_type(4)));
typedef float    f32x8  __attribute__((ext_vector_type(8)));
typedef unsigned short us4 __attribute__((ext_vector_type(4)));

// RNE float -> bf16 bits (finite inputs; no NaN path needed)
__device__ __forceinline__ unsigned short f2bf(float f) {
  unsigned int u = __float_as_uint(f);
  u = (u + 0x7fffu + ((u >> 16) & 1u)) >> 16;
  return (unsigned short)u;
}

// ---------------------------------------------------------------------------
// Pack kernel: sub_W [E][D][K] fp32 -> Bp [E][K][D] bf16 in d_ws.
// Thread t: k = t&31, g = t>>5, d0 = (g%96)*8, e = g/96.
// For fixed (g,j) the 32 lanes of a half-wave read 128 B contiguous (coalesced);
// write is one short8 per thread.
// ---------------------------------------------------------------------------
__global__ __launch_bounds__(256) void pack_w(const float* __restrict__ sw,
                                              short* __restrict__ bp) {
  const int t  = blockIdx.x * 256 + threadIdx.x;   // 0 .. 24575
  const int k  = t & 31;
  const int g  = t >> 5;            // 0..767
  const int d0 = (g % 96) * 8;
  const int e  = g / 96;
  const float* src = sw + ((size_t)(e * DD + d0)) * KK + k;
  short8 v;
#pragma unroll
  for (int j = 0; j < 8; ++j) v[j] = (short)f2bf(src[(size_t)j * KK]);
  *(short8*)(bp + ((size_t)(e * KK + k)) * DD + d0) = v;
}

// ---------------------------------------------------------------------------
// Fused kernel: 1024 threads (16 waves), 32 rows per block, 256 blocks.
// Phase 1: wave w computes fp32 main logits for rows {2w, 2w+1} (exact argmax
//          source), stashing pooled as bf16 into LDS along the way.
// Phase 2: waves w and w+8 both handle expert (w&7), splitting the K-range
//          (ks 0-11 vs 12-23); partial accumulators reduced through LDS
//          (reusing the A-tile buffer after a barrier).
// Epilogue: waves 0-7 do routed select + bias + size mask; each (row,k) once.
// ---------------------------------------------------------------------------
__global__ __launch_bounds__(1024) void fused(
    const float* __restrict__ pooled, const float* __restrict__ mW,
    const float* __restrict__ mb, const short* __restrict__ Bp,
    const float* __restrict__ sub_b, const int* __restrict__ sub_sizes,
    float* __restrict__ main_out, float* __restrict__ sub_out) {
  // 776 = 768 + 8 shorts pad (row stride 1552 B). 48.5 KB; reused as the
  // 32 KB fp32 partial-reduction buffer after the K-loop barrier.
  __shared__ short aS[32][776];
  __shared__ int   idxS[32];
  __shared__ int   szS[32];

  const int t    = threadIdx.x;
  const int w    = t >> 6;
  const int lane = t & 63;
  const int row0 = blockIdx.x * 32;

  // ---- Phase 1: main GEMV (fp32) + bf16 stash, 2 rows per wave ----
  f32x8 acc[2] = {};
#pragma unroll
  for (int i = 0; i < 3; ++i) {
    const int d = (i * 64 + lane) * 4;
    f32x8 W0 = *(const f32x8*)(mW + (size_t)(d + 0) * EE);
    f32x8 W1 = *(const f32x8*)(mW + (size_t)(d + 1) * EE);
    f32x8 W2 = *(const f32x8*)(mW + (size_t)(d + 2) * EE);
    f32x8 W3 = *(const f32x8*)(mW + (size_t)(d + 3) * EE);
#pragma unroll
    for (int rr = 0; rr < 2; ++rr) {
      const int r = w * 2 + rr;
      f32x4 v = *(const f32x4*)(pooled + (size_t)(row0 + r) * DD + d);
      us4 u;
      u[0] = f2bf(v[0]); u[1] = f2bf(v[1]); u[2] = f2bf(v[2]); u[3] = f2bf(v[3]);
      *(us4*)&aS[r][d] = u;
      acc[rr] += v[0] * W0;
      acc[rr] += v[1] * W1;
      acc[rr] += v[2] * W2;
      acc[rr] += v[3] * W3;
    }
  }
#pragma unroll
  for (int rr = 0; rr < 2; ++rr) {
#pragma unroll
    for (int off = 32; off >= 1; off >>= 1) {
#pragma unroll
      for (int j = 0; j < 8; ++j) acc[rr][j] += __shfl_xor(acc[rr][j], off);
    }
    if (lane == 0) {
      const int r = w * 2 + rr;
      f32x8 res = acc[rr] + *(const f32x8*)mb;
      *(f32x8*)(main_out + (size_t)(row0 + r) * EE) = res;
      float best = res[0];
      int   bi   = 0;
#pragma unroll
      for (int e = 1; e < EE; ++e) {
        if (res[e] > best) { best = res[e]; bi = e; }
      }
      idxS[r] = bi;
      szS[r]  = sub_sizes[bi];
    }
  }
  __syncthreads();

  // ---- Phase 2: MFMA, expert e = w&7, K-range half = w>>3 ----
  const int e    = w & 7;
  const int half = w >> 3;
  const int lc   = lane & 15, hi = lane >> 4;
  const short* bb  = Bp + (size_t)e * KK * DD + (size_t)hi * 8;
  const short* bp0 = bb + (size_t)lc * DD;          // k = lc
  const short* bp1 = bb + (size_t)(16 + lc) * DD;   // k = 16 + lc
  f32x4 a2[2][2] = {};
  const int ks0 = half * 12;

#pragma unroll
  for (int ii = 0; ii < 12; ++ii) {
    const int ks = ks0 + ii;
    const int d0 = ks * 32 + hi * 8;
    short8 b0 = *(const short8*)(bp0 + ks * 32);
    short8 b1 = *(const short8*)(bp1 + ks * 32);
    short8 a0 = *(const short8*)&aS[lc][d0];
    short8 a1 = *(const short8*)&aS[16 + lc][d0];
    a2[0][0] = __builtin_amdgcn_mfma_f32_16x16x32_bf16(a0, b0, a2[0][0], 0, 0, 0);
    a2[0][1] = __builtin_amdgcn_mfma_f32_16x16x32_bf16(a0, b1, a2[0][1], 0, 0, 0);
    a2[1][0] = __builtin_amdgcn_mfma_f32_16x16x32_bf16(a1, b0, a2[1][0], 0, 0, 0);
    a2[1][1] = __builtin_amdgcn_mfma_f32_16x16x32_bf16(a1, b1, a2[1][1], 0, 0, 0);
  }
  __syncthreads();   // all A-reads done; aS reusable as reduction buffer

  // red layout [ai][e][lane] f32x4: lane-contiguous 16 B -> conflict-free.
  f32x4* red = (f32x4*)&aS[0][0];
#define RI(ai) (((ai) * 8 + e) * 64 + lane)
  if (half) {
    red[RI(0)] = a2[0][0];
    red[RI(1)] = a2[0][1];
    red[RI(2)] = a2[1][0];
    red[RI(3)] = a2[1][1];
  }
  __syncthreads();

  if (!half) {
    a2[0][0] += red[RI(0)];
    a2[0][1] += red[RI(1)];
    a2[1][0] += red[RI(2)];
    a2[1][1] += red[RI(3)];
#undef RI
    // ---- Epilogue: routed select + bias + size mask ----
#pragma unroll
    for (int n = 0; n < 2; ++n) {
      const int k = n * 16 + lc;
      const float bias = sub_b[e * KK + k];
#pragma unroll
      for (int mt = 0; mt < 2; ++mt) {
#pragma unroll
        for (int q = 0; q < 4; ++q) {
          const int rl = mt * 16 + hi * 4 + q;  // C/D: col=lane&15, row=(l>>4)*4+q
          if (idxS[rl] == e) {
            float v = a2[mt][n][q] + bias;
            if (k >= szS[rl]) v = 0.f;
            sub_out[(size_t)(row0 + rl) * KK + k] = v;
          }
        }
      }
    }
  }
}

// ---------------------------------------------------------------------------
extern "C" void kernel_launch(void* const* d_in, const int* in_sizes, int n_in,
                              void* d_out, int out_size, void* d_ws, size_t ws_size,
                              hipStream_t stream) {
  const float* pooled   = (const float*)d_in[0];
  const float* main_W   = (const float*)d_in[1];
  const float* main_b   = (const float*)d_in[2];
  const float* sub_W    = (const float*)d_in[3];
  const float* sub_b    = (const float*)d_in[4];
  const int*   sub_size = (const int*)d_in[5];

  float* main_out = (float*)d_out;                    // [B, E]
  float* sub_out  = (float*)d_out + (size_t)BB * EE;  // [B, K]
  short* Bp       = (short*)d_ws;                     // [E][K][D] bf16, 384 KB

  pack_w<<<(EE * KK * DD / 8) / 256, 256, 0, stream>>>(sub_W, Bp);
  fused<<<BB / 32, 1024, 0, stream>>>(pooled, main_W, main_b, Bp, sub_b,
                                      sub_size, main_out, sub_out);
}

// Round 4
// 41.030 us; speedup vs baseline: 1.0304x; 1.0304x over previous
//
#include <hip/hip_runtime.h>

// Problem constants (HierarchicalIntentClassifier: B=8192, D=768, E=8, K=32)
#define BB 8192
#define DD 768
#define EE 8
#define KK 32

typedef short    short8 __attribute__((ext_vector_type(8)));
typedef float    f32x4  __attribute__((ext_vector_type(4)));
typedef float    f32x8  __attribute__((ext_vector_type(8)));
typedef unsigned short us4 __attribute__((ext_vector_type(4)));

// RNE float -> bf16 bits (finite inputs; no NaN path needed)
__device__ __forceinline__ unsigned short f2bf(float f) {
  unsigned int u = __float_as_uint(f);
  u = (u + 0x7fffu + ((u >> 16) & 1u)) >> 16;
  return (unsigned short)u;
}

// ---------------------------------------------------------------------------
// Pack kernel: sub_W [E][D][K] fp32 -> Bp [E][K][D] bf16 in d_ws.
// Half-wave-coalesced reads (128 B per 32 lanes per j), short8 writes.
// ---------------------------------------------------------------------------
__global__ __launch_bounds__(256) void pack_w(const float* __restrict__ sw,
                                              short* __restrict__ bp) {
  const int t  = blockIdx.x * 256 + threadIdx.x;   // 0 .. 24575
  const int k  = t & 31;
  const int g  = t >> 5;            // 0..767
  const int d0 = (g % 96) * 8;
  const int e  = g / 96;
  const float* src = sw + ((size_t)(e * DD + d0)) * KK + k;
  short8 v;
#pragma unroll
  for (int j = 0; j < 8; ++j) v[j] = (short)f2bf(src[(size_t)j * KK]);
  *(short8*)(bp + ((size_t)(e * KK + k)) * DD + d0) = v;
}

// ---------------------------------------------------------------------------
// Fused kernel: 1024 threads (16 waves, 4 waves/SIMD), 32 rows/block, 256 blk.
// Phase 1: wave w computes fp32 main logits for rows {2w, 2w+1} (exact argmax
//          source), stashing pooled as bf16 into LDS along the way.
// Phase 2: N-split (NOT K-split): wave w owns expert w>>1 and k-half w&1.
//          Full K-loop per wave, 1 B-load + 2 A-reads + 2 MFMA per step.
//          No reduction, no extra barriers; all waves write the epilogue.
// Exactly ONE __syncthreads in the kernel.
// ---------------------------------------------------------------------------
__global__ __launch_bounds__(1024) void fused(
    const float* __restrict__ pooled, const float* __restrict__ mW,
    const float* __restrict__ mb, const short* __restrict__ Bp,
    const float* __restrict__ sub_b, const int* __restrict__ sub_sizes,
    float* __restrict__ main_out, float* __restrict__ sub_out) {
  // 776 = 768 + 8 shorts pad (row stride 1552 B): breaks the power-of-2
  // column->bank aliasing on ds_read_b128 (~2-way residual, free on CDNA4).
  __shared__ short aS[32][776];
  __shared__ int   idxS[32];
  __shared__ int   szS[32];

  const int t    = threadIdx.x;
  const int w    = t >> 6;
  const int lane = t & 63;
  const int row0 = blockIdx.x * 32;

  // ---- Phase 1: main GEMV (fp32) + bf16 stash, 2 rows per wave ----
  f32x8 acc[2] = {};
#pragma unroll
  for (int i = 0; i < 3; ++i) {
    const int d = (i * 64 + lane) * 4;
    f32x8 W0 = *(const f32x8*)(mW + (size_t)(d + 0) * EE);
    f32x8 W1 = *(const f32x8*)(mW + (size_t)(d + 1) * EE);
    f32x8 W2 = *(const f32x8*)(mW + (size_t)(d + 2) * EE);
    f32x8 W3 = *(const f32x8*)(mW + (size_t)(d + 3) * EE);
#pragma unroll
    for (int rr = 0; rr < 2; ++rr) {
      const int r = w * 2 + rr;
      f32x4 v = *(const f32x4*)(pooled + (size_t)(row0 + r) * DD + d);
      us4 u;
      u[0] = f2bf(v[0]); u[1] = f2bf(v[1]); u[2] = f2bf(v[2]); u[3] = f2bf(v[3]);
      *(us4*)&aS[r][d] = u;
      acc[rr] += v[0] * W0;
      acc[rr] += v[1] * W1;
      acc[rr] += v[2] * W2;
      acc[rr] += v[3] * W3;
    }
  }
#pragma unroll
  for (int rr = 0; rr < 2; ++rr) {
#pragma unroll
    for (int off = 32; off >= 1; off >>= 1) {
#pragma unroll
      for (int j = 0; j < 8; ++j) acc[rr][j] += __shfl_xor(acc[rr][j], off);
    }
    if (lane == 0) {
      const int r = w * 2 + rr;
      f32x8 res = acc[rr] + *(const f32x8*)mb;
      *(f32x8*)(main_out + (size_t)(row0 + r) * EE) = res;
      float best = res[0];
      int   bi   = 0;
#pragma unroll
      for (int e = 1; e < EE; ++e) {
        if (res[e] > best) { best = res[e]; bi = e; }
      }
      idxS[r] = bi;
      szS[r]  = sub_sizes[bi];
    }
  }
  __syncthreads();

  // ---- Phase 2: MFMA. Wave w: expert e = w>>1, k-half n = w&1. Full K. ----
  const int e  = w >> 1;
  const int nh = w & 1;
  const int lc = lane & 15, hi = lane >> 4;
  const int k  = nh * 16 + lc;                      // this wave's output col
  const short* bp = Bp + ((size_t)e * KK + k) * DD + (size_t)hi * 8;
  f32x4 a2[2] = {};                                 // M-tiles 0 (rows 0-15), 1

  for (int ks = 0; ks < DD / 32; ++ks) {
    const int d0 = ks * 32 + hi * 8;
    short8 b0 = *(const short8*)(bp + ks * 32);
    short8 a0 = *(const short8*)&aS[lc][d0];
    short8 a1 = *(const short8*)&aS[16 + lc][d0];
    a2[0] = __builtin_amdgcn_mfma_f32_16x16x32_bf16(a0, b0, a2[0], 0, 0, 0);
    a2[1] = __builtin_amdgcn_mfma_f32_16x16x32_bf16(a1, b0, a2[1], 0, 0, 0);
  }

  // ---- Epilogue: routed select + bias + size mask; each (row,k) once ----
  const float bias = sub_b[e * KK + k];
#pragma unroll
  for (int mt = 0; mt < 2; ++mt) {
#pragma unroll
    for (int q = 0; q < 4; ++q) {
      const int rl = mt * 16 + hi * 4 + q;   // C/D: col=lane&15, row=(l>>4)*4+q
      if (idxS[rl] == e) {
        float v = a2[mt][q] + bias;
        if (k >= szS[rl]) v = 0.f;
        sub_out[(size_t)(row0 + rl) * KK + k] = v;
      }
    }
  }
}

// ---------------------------------------------------------------------------
extern "C" void kernel_launch(void* const* d_in, const int* in_sizes, int n_in,
                              void* d_out, int out_size, void* d_ws, size_t ws_size,
                              hipStream_t stream) {
  const float* pooled   = (const float*)d_in[0];
  const float* main_W   = (const float*)d_in[1];
  const float* main_b   = (const float*)d_in[2];
  const float* sub_W    = (const float*)d_in[3];
  const float* sub_b    = (const float*)d_in[4];
  const int*   sub_size = (const int*)d_in[5];

  float* main_out = (float*)d_out;                    // [B, E]
  float* sub_out  = (float*)d_out + (size_t)BB * EE;  // [B, K]
  short* Bp       = (short*)d_ws;                     // [E][K][D] bf16, 384 KB

  pack_w<<<(EE * KK * DD / 8) / 256, 256, 0, stream>>>(sub_W, Bp);
  fused<<<BB / 32, 1024, 0, stream>>>(pooled, main_W, main_b, Bp, sub_b,
                                      sub_size, main_out, sub_out);
}